// Round 10
// baseline (6109.182 us; speedup 1.0000x reference)
//
#include <hip/hip_runtime.h>

#define T_STEPS 2048
#define TOTAL   2088   // T_STEPS + 40 (deepest lag: TT)

typedef float f2 __attribute__((ext_vector_type(2)));

__device__ __forceinline__ float fast_rcp(float x) { return __builtin_amdgcn_rcpf(x); }
__device__ __forceinline__ float sig_f(float x) { return fast_rcp(1.0f + __expf(-x)); }
__device__ __forceinline__ float tanh_f(float x) {
    float e = __expf(-2.0f * x);
    return fmaf(2.0f, fast_rcp(1.0f + e), -1.0f);
}
__device__ __forceinline__ float gate_act(float x, float zm, float sm, float sa) {
    float e = __expf(-x * zm);
    return fmaf(fast_rcp(1.0f + e), sm, sa);
}

// Drain ONLY lgkmcnt (LDS) before barrier — never vmcnt (R7 win).
#define LDS_BARRIER() asm volatile("s_waitcnt lgkmcnt(0)\n\ts_barrier" ::: "memory")

#define DPP_BCAST0 0x00
#define DPP_BCAST1 0x55
#define DPP_BCAST2 0xAA
#define DPP_BCAST3 0xFF
#define DPP_ROR4   0x124
#define DPP_ROR8   0x128
template<int CTRL>
__device__ __forceinline__ float dppf(float x) {
    int r = __builtin_amdgcn_update_dpp(0, __builtin_bit_cast(int, x), CTRL, 0xF, 0xF, true);
    return __builtin_bit_cast(float, r);
}

__device__ __forceinline__ void ld24(f2 (&d)[24], const float* __restrict__ p) {
    const f2* q = (const f2*)p;
#pragma unroll
    for (int k = 0; k < 24; ++k) d[k] = q[k];
}

__device__ __forceinline__ float4 dot4(const f2 (&in)[24], const f2 (&w)[4][24], float4 init) {
    f2 a0 = f2{init.x, 0.f}, a1 = f2{init.y, 0.f}, a2 = f2{init.z, 0.f}, a3 = f2{init.w, 0.f};
#pragma unroll
    for (int u = 0; u < 24; ++u) {
        a0 = __builtin_elementwise_fma(w[0][u], in[u], a0);
        a1 = __builtin_elementwise_fma(w[1][u], in[u], a1);
        a2 = __builtin_elementwise_fma(w[2][u], in[u], a2);
        a3 = __builtin_elementwise_fma(w[3][u], in[u], a3);
    }
    return float4{a0.x + a0.y, a1.x + a1.y, a2.x + a2.y, a3.x + a3.y};
}

__device__ __forceinline__ float cellh(float4 pre, float& c) {
    float iv = sig_f(pre.x), fv = sig_f(pre.y);
    float gv = tanh_f(pre.z), ov = sig_f(pre.w);
    c = fmaf(fv, c, iv * gv);
    return ov * tanh_f(c);
}

__device__ __forceinline__ void loadx4(float (&dst)[4], const float* __restrict__ x_r,
                                       const float* __restrict__ x_t,
                                       size_t xrb, size_t xtb, int l) {
#pragma unroll
    for (int u = 0; u < 4; ++u) {
        int v = l + 16 * u;
        dst[u] = (v < 47) ? x_r[xrb + v] : ((v < 49) ? x_t[xtb + (v - 47)] : 0.0f);
    }
}

__global__ __launch_bounds__(320, 1) void adrnn_fused(
    const float* __restrict__ x_r, const float* __restrict__ x_t,
    const float* __restrict__ rWih0, const float* __restrict__ rWhh0,
    const float* __restrict__ rbih0, const float* __restrict__ rbhh0,
    const float* __restrict__ rWih1, const float* __restrict__ rWhh1,
    const float* __restrict__ rbih1, const float* __restrict__ rbhh1,
    const float* __restrict__ tWih0, const float* __restrict__ tWhh0,
    const float* __restrict__ tbih0, const float* __restrict__ tbhh0,
    const float* __restrict__ tWih1, const float* __restrict__ tWhh1,
    const float* __restrict__ tbih1, const float* __restrict__ tbhh1,
    float* __restrict__ r_out, float* __restrict__ t_out)
{
    // Rings; rows padded for bank spread. All cross-wave prefetch targets are
    // written in a strictly earlier 8-step group (group barrier = visibility).
    __shared__ __align__(16) float tring[64][128]; // [x 0..48 | pad | h1 64..110 | pad 111..]
    __shared__ __align__(16) float h0ring[16][48];
    __shared__ __align__(16) float pAring[16][192];
    __shared__ __align__(16) float pBring[16][192];

    const int tid = threadIdx.x;
    const int wid = tid >> 6;
    const int l   = tid & 63;
    const int j   = l;
    const int b = blockIdx.x;
    const size_t xr_base = (size_t)b * T_STEPS * 47;
    const size_t xt_base = (size_t)b * T_STEPS * 2;

    if (tid < 256) {
        for (int k = tid; k < 64 * 48; k += 256) tring[k / 48][64 + (k % 48)] = 0.0f;
        for (int k = tid; k < 16 * 48; k += 256) h0ring[k / 48][k % 48] = 0.0f;
    }

    if (wid == 0) {
        // ===== XA (lag 0): pA(i) = Wih0*x(i)+b0 =====
        f2 w[4][24]; float w48[4]; float4 bias = {0,0,0,0};
#pragma unroll
        for (int g = 0; g < 4; ++g) { w48[g] = 0.f;
#pragma unroll
            for (int u = 0; u < 24; ++u) w[g][u] = f2{0.f, 0.f}; }
        if (j < 47) {
            float bb[4];
#pragma unroll
            for (int g = 0; g < 4; ++g) {
                const int row = g * 47 + j;
#pragma unroll
                for (int u = 0; u < 24; ++u)
                    w[g][u] = f2{rWih0[row * 49 + 2 * u], rWih0[row * 49 + 2 * u + 1]};
                w48[g] = rWih0[row * 49 + 48];
                bb[g] = rbih0[row] + rbhh0[row];
            }
            bias = {bb[0], bb[1], bb[2], bb[3]};
        }
        f2 bufA[24], bufB[24]; float xA = 0.f, xB = 0.f;
        auto PF = [&](int i, f2 (&buf)[24], float& bx) {
            if ((unsigned)i < T_STEPS) { ld24(buf, &tring[i & 63][0]); bx = tring[i & 63][48]; }
        };
        auto CMP = [&](int i, const f2 (&buf)[24], float bx) {
            if ((unsigned)i < T_STEPS && j < 47) {
                float4 pre = dot4(buf, w, bias);
                pre.x = fmaf(w48[0], bx, pre.x); pre.y = fmaf(w48[1], bx, pre.y);
                pre.z = fmaf(w48[2], bx, pre.z); pre.w = fmaf(w48[3], bx, pre.w);
                *(float4*)&pAring[i & 15][j * 4] = pre;
            }
        };
        __syncthreads();
        PF(0, bufA, xA);
        for (int ii = 0; ii < TOTAL; ii += 2) {
            PF(ii + 1, bufB, xB);
            CMP(ii, bufA, xA);
            if (((ii + 1) & 7) == 7) { CMP(ii + 1, bufB, xB); LDS_BARRIER(); PF(ii + 2, bufA, xA); }
            else                     { PF(ii + 2, bufA, xA); CMP(ii + 1, bufB, xB); }
        }
    } else if (wid == 1) {
        // ===== HA (lag 8): h0(s) = cell(pA(s) + Whh0*h0(s-1)) =====
        f2 w[4][24];
#pragma unroll
        for (int g = 0; g < 4; ++g)
#pragma unroll
            for (int u = 0; u < 24; ++u) w[g][u] = f2{0.f, 0.f};
        if (j < 47) {
#pragma unroll
            for (int g = 0; g < 4; ++g) {
                const int row = g * 47 + j;
#pragma unroll
                for (int u = 0; u < 23; ++u)
                    w[g][u] = f2{rWhh0[row * 47 + 2 * u], rWhh0[row * 47 + 2 * u + 1]};
                w[g][23] = f2{rWhh0[row * 47 + 46], 0.f};
            }
        }
        float c0 = 0.f;
        float4 paA = {0,0,0,0}, paB = {0,0,0,0};
        auto PF = [&](int i, float4& pa) {
            int s = i - 8;
            if ((unsigned)s < T_STEPS && j < 47) pa = *(const float4*)&pAring[s & 15][j * 4];
        };
        auto CMP = [&](int i, float4 pa) {
            int s = i - 8;
            if ((unsigned)s < T_STEPS && j < 47) {
                f2 hin[24];
                ld24(hin, &h0ring[(s - 1) & 15][0]);     // in-chain (recurrent)
                float4 pre = dot4(hin, w, pa);
                float h = cellh(pre, c0);
                h0ring[s & 15][j] = h;
            }
        };
        __syncthreads();
        PF(0, paA);
        for (int ii = 0; ii < TOTAL; ii += 2) {
            PF(ii + 1, paB);
            CMP(ii, paA);
            if (((ii + 1) & 7) == 7) { CMP(ii + 1, paB); LDS_BARRIER(); PF(ii + 2, paA); }
            else                     { PF(ii + 2, paA); CMP(ii + 1, paB); }
        }
    } else if (wid == 2) {
        // ===== XB (lag 16): pB(s) = Wih1*h0(s)+b1 =====
        f2 w[4][24]; float4 bias = {0,0,0,0};
#pragma unroll
        for (int g = 0; g < 4; ++g)
#pragma unroll
            for (int u = 0; u < 24; ++u) w[g][u] = f2{0.f, 0.f};
        if (j < 47) {
            float bb[4];
#pragma unroll
            for (int g = 0; g < 4; ++g) {
                const int row = g * 47 + j;
#pragma unroll
                for (int u = 0; u < 23; ++u)
                    w[g][u] = f2{rWih1[row * 47 + 2 * u], rWih1[row * 47 + 2 * u + 1]};
                w[g][23] = f2{rWih1[row * 47 + 46], 0.f};
                bb[g] = rbih1[row] + rbhh1[row];
            }
            bias = {bb[0], bb[1], bb[2], bb[3]};
        }
        f2 bufA[24], bufB[24];
        auto PF = [&](int i, f2 (&buf)[24]) {
            int s = i - 16;
            if ((unsigned)s < T_STEPS) ld24(buf, &h0ring[s & 15][0]);
        };
        auto CMP = [&](int i, const f2 (&buf)[24]) {
            int s = i - 16;
            if ((unsigned)s < T_STEPS && j < 47) {
                float4 pre = dot4(buf, w, bias);
                *(float4*)&pBring[s & 15][j * 4] = pre;
            }
        };
        __syncthreads();
        PF(0, bufA);
        for (int ii = 0; ii < TOTAL; ii += 2) {
            PF(ii + 1, bufB);
            CMP(ii, bufA);
            if (((ii + 1) & 7) == 7) { CMP(ii + 1, bufB); LDS_BARRIER(); PF(ii + 2, bufA); }
            else                     { PF(ii + 2, bufA); CMP(ii + 1, bufB); }
        }
    } else if (wid == 3) {
        // ===== HB (lag 24): h1(s) = cell(pB(s) + Whh1*h1(s-1)) =====
        f2 w[4][24];
#pragma unroll
        for (int g = 0; g < 4; ++g)
#pragma unroll
            for (int u = 0; u < 24; ++u) w[g][u] = f2{0.f, 0.f};
        if (j < 47) {
#pragma unroll
            for (int g = 0; g < 4; ++g) {
                const int row = g * 47 + j;
#pragma unroll
                for (int u = 0; u < 23; ++u)
                    w[g][u] = f2{rWhh1[row * 47 + 2 * u], rWhh1[row * 47 + 2 * u + 1]};
                w[g][23] = f2{rWhh1[row * 47 + 46], 0.f};
            }
        }
        float c1 = 0.f;
        float4 pbA = {0,0,0,0}, pbB = {0,0,0,0};
        auto PF = [&](int i, float4& pb) {
            int s = i - 24;
            if ((unsigned)s < T_STEPS && j < 47) pb = *(const float4*)&pBring[s & 15][j * 4];
        };
        auto CMP = [&](int i, float4 pb) {
            int s = i - 24;
            if ((unsigned)s < T_STEPS && j < 47) {
                f2 hin[24];
                ld24(hin, &tring[(s - 1) & 63][64]);     // in-chain (recurrent), [111]=0
                float4 pre = dot4(hin, w, pb);
                float h = cellh(pre, c1);
                tring[s & 63][64 + j] = h;
                r_out[((size_t)b * T_STEPS + s) * 47 + j] = h;
            }
        };
        __syncthreads();
        PF(0, pbA);
        for (int ii = 0; ii < TOTAL; ii += 2) {
            PF(ii + 1, pbB);
            CMP(ii, pbA);
            if (((ii + 1) & 7) == 7) { CMP(ii + 1, pbB); LDS_BARRIER(); PF(ii + 2, pbA); }
            else                     { PF(ii + 2, pbA); CMP(ii + 1, pbB); }
        }
    } else {
        // ===== TT (lag 40): t-RNN + x staging (8 ahead) =====
        const int u  = (l >> 2) & 1;
        const int g  = l & 3;
        const int hf = (l >> 3) & 1;
        const int R0 = g * 2 + u;
        f2 wt[24]; float wx48;
        if (hf == 0) {
            wx48 = 0.f;
#pragma unroll
            for (int k = 0; k < 24; ++k)
                wt[k] = f2{tWih0[R0 * 96 + 2 * k], tWih0[R0 * 96 + 2 * k + 1]};
        } else {
            wx48 = tWih0[R0 * 96 + 48];
#pragma unroll
            for (int k = 0; k < 23; ++k)
                wt[k] = f2{tWih0[R0 * 96 + 49 + 2 * k], tWih0[R0 * 96 + 49 + 2 * k + 1]};
            wt[23] = f2{tWih0[R0 * 96 + 95], 0.f};
        }
        const float bT0 = tbih0[R0] + tbhh0[R0];
        const float wh00 = tWhh0[R0 * 2 + 0], wh01 = tWhh0[R0 * 2 + 1];
        const float wi10 = tWih1[R0 * 2 + 0], wi11 = tWih1[R0 * 2 + 1];
        const float wh10 = tWhh1[R0 * 2 + 0], wh11 = tWhh1[R0 * 2 + 1];
        const float bT1 = tbih1[R0] + tbhh1[R0];
        const bool isg = (g == 2);
        const float zm = isg ? 2.f : 1.f, sm = isg ? 2.f : 1.f, sa = isg ? -1.f : 0.f;
        float ht00 = 0.f, ht01 = 0.f, ct0u = 0.f;
        float ht10 = 0.f, ht11 = 0.f, ct1u = 0.f;

        float xa[4] = {0,0,0,0}, xb[4] = {0,0,0,0}, xc[4] = {0,0,0,0};
        f2 tA[24], tB[24]; float xqA = 0.f, xqB = 0.f;

        auto PF = [&](int i, f2 (&buf)[24], float& xq) {
            int s = i - 40;
            if ((unsigned)s < T_STEPS) {
                ld24(buf, &tring[s & 63][hf ? 64 : 0]);
                xq = tring[s & 63][48];
            }
        };
        auto STG = [&](int i) {
            if (l < 16) {
                const int tw = i + 8;
                if (tw < T_STEPS) {
#pragma unroll
                    for (int uu = 0; uu < 4; ++uu) {
                        int v = l + 16 * uu;
                        if (v < 49) tring[tw & 63][v] = xa[uu];
                    }
                }
#pragma unroll
                for (int uu = 0; uu < 4; ++uu) { xa[uu] = xb[uu]; xb[uu] = xc[uu]; }
                int tl = i + 11;
                if (tl > T_STEPS - 1) tl = T_STEPS - 1;
                loadx4(xc, x_r, x_t, xr_base + (size_t)tl * 47, xt_base + (size_t)tl * 2, l);
            }
        };
        auto CMP = [&](int i, const f2 (&buf)[24], float xq) {
            int s = i - 40;
            if ((unsigned)s < T_STEPS) {
                f2 av = {0,0}, bv = {0,0};
#pragma unroll
                for (int k = 0; k < 12; ++k) {
                    av = __builtin_elementwise_fma(wt[2 * k],     buf[2 * k],     av);
                    bv = __builtin_elementwise_fma(wt[2 * k + 1], buf[2 * k + 1], bv);
                }
                f2 sv = av + bv;
                float part = fmaf(wx48, xq, sv.x + sv.y);
                float pre0 = part + dppf<DPP_ROR8>(part);
                pre0 += bT0 + wh00 * ht00 + wh01 * ht01;
                float a0 = gate_act(pre0, zm, sm, sa);
                float i0 = dppf<DPP_BCAST0>(a0);
                float f0 = dppf<DPP_BCAST1>(a0);
                float g0 = dppf<DPP_BCAST2>(a0);
                float o0 = dppf<DPP_BCAST3>(a0);
                ct0u = fmaf(f0, ct0u, i0 * g0);
                float htu = o0 * tanh_f(ct0u);
                float hto = dppf<DPP_ROR4>(htu);
                ht00 = (u == 0) ? htu : hto;
                ht01 = (u == 0) ? hto : htu;
                float pre1 = bT1 + wi10 * ht00 + wi11 * ht01 + wh10 * ht10 + wh11 * ht11;
                float a1 = gate_act(pre1, zm, sm, sa);
                float ji = dppf<DPP_BCAST0>(a1);
                float jf = dppf<DPP_BCAST1>(a1);
                float jg = dppf<DPP_BCAST2>(a1);
                float jo = dppf<DPP_BCAST3>(a1);
                ct1u = fmaf(jf, ct1u, ji * jg);
                float h1u = jo * tanh_f(ct1u);
                float h1o = dppf<DPP_ROR4>(h1u);
                ht10 = (u == 0) ? h1u : h1o;
                ht11 = (u == 0) ? h1o : h1u;
                if (l == 0) {
                    float2 tv = {ht10, ht11};
                    *reinterpret_cast<float2*>(&t_out[((size_t)b * T_STEPS + s) * 2]) = tv;
                }
            }
        };

        // prologue: stage x(0..7); prefetch regs x(8..10)
        if (l < 16) {
            for (int t = 0; t < 8; ++t) {
                float xv[4];
                loadx4(xv, x_r, x_t, xr_base + (size_t)t * 47, xt_base + (size_t)t * 2, l);
#pragma unroll
                for (int uu = 0; uu < 4; ++uu) {
                    int v = l + 16 * uu;
                    if (v < 49) tring[t][v] = xv[uu];
                }
            }
            loadx4(xa, x_r, x_t, xr_base + (size_t)8 * 47,  xt_base + (size_t)8 * 2,  l);
            loadx4(xb, x_r, x_t, xr_base + (size_t)9 * 47,  xt_base + (size_t)9 * 2,  l);
            loadx4(xc, x_r, x_t, xr_base + (size_t)10 * 47, xt_base + (size_t)10 * 2, l);
        }
        __syncthreads();
        PF(0, tA, xqA);
        for (int ii = 0; ii < TOTAL; ii += 2) {
            STG(ii);
            PF(ii + 1, tB, xqB);
            CMP(ii, tA, xqA);
            STG(ii + 1);
            if (((ii + 1) & 7) == 7) { CMP(ii + 1, tB, xqB); LDS_BARRIER(); PF(ii + 2, tA, xqA); }
            else                     { PF(ii + 2, tA, xqA); CMP(ii + 1, tB, xqB); }
        }
    }
}

extern "C" void kernel_launch(void* const* d_in, const int* in_sizes, int n_in,
                              void* d_out, int out_size, void* d_ws, size_t ws_size,
                              hipStream_t stream) {
    const float* x_r   = (const float*)d_in[0];
    const float* x_t   = (const float*)d_in[1];
    const float* rWih0 = (const float*)d_in[2];
    const float* rWhh0 = (const float*)d_in[3];
    const float* rbih0 = (const float*)d_in[4];
    const float* rbhh0 = (const float*)d_in[5];
    const float* rWih1 = (const float*)d_in[6];
    const float* rWhh1 = (const float*)d_in[7];
    const float* rbih1 = (const float*)d_in[8];
    const float* rbhh1 = (const float*)d_in[9];
    const float* tWih0 = (const float*)d_in[10];
    const float* tWhh0 = (const float*)d_in[11];
    const float* tbih0 = (const float*)d_in[12];
    const float* tbhh0 = (const float*)d_in[13];
    const float* tWih1 = (const float*)d_in[14];
    const float* tWhh1 = (const float*)d_in[15];
    const float* tbih1 = (const float*)d_in[16];
    const float* tbhh1 = (const float*)d_in[17];

    float* r_out = (float*)d_out;
    float* t_out = r_out + (size_t)256 * T_STEPS * 47;

    hipLaunchKernelGGL(adrnn_fused, dim3(256), dim3(320), 0, stream,
                       x_r, x_t, rWih0, rWhh0, rbih0, rbhh0, rWih1, rWhh1, rbih1, rbhh1,
                       tWih0, tWhh0, tbih0, tbhh0, tWih1, tWhh1, tbih1, tbhh1,
                       r_out, t_out);
}

// Round 11
// 1443.055 us; speedup vs baseline: 4.2335x; 4.2335x over previous
//
#include <hip/hip_runtime.h>

#define T_STEPS 2048
#define TOTAL   2080   // T_STEPS + 32 (deepest lag)

typedef float f2 __attribute__((ext_vector_type(2)));

__device__ __forceinline__ float fast_rcp(float x) { return __builtin_amdgcn_rcpf(x); }

__device__ __forceinline__ float sig_f(float x) {
    return fast_rcp(1.0f + __expf(-x));
}
__device__ __forceinline__ float tanh_f(float x) {
    float e = __expf(-2.0f * x);
    return fmaf(2.0f, fast_rcp(1.0f + e), -1.0f);
}
__device__ __forceinline__ float gate_act(float x, float zm, float sm, float sa) {
    float e = __expf(-x * zm);
    return fmaf(fast_rcp(1.0f + e), sm, sa);
}

// Drain ONLY lgkmcnt (LDS) before barrier — never vmcnt (R7 win).
#define LDS_BARRIER() asm volatile("s_waitcnt lgkmcnt(0)\n\ts_barrier" ::: "memory")

#define DPP_BCAST0 0x00
#define DPP_BCAST1 0x55
#define DPP_BCAST2 0xAA
#define DPP_BCAST3 0xFF
#define DPP_ROR4   0x124
#define DPP_ROR8   0x128
template<int CTRL>
__device__ __forceinline__ float dppf(float x) {
    int r = __builtin_amdgcn_update_dpp(0, __builtin_bit_cast(int, x), CTRL, 0xF, 0xF, true);
    return __builtin_bit_cast(float, r);
}

__device__ __forceinline__ void loadx4(float (&dst)[4], const float* __restrict__ x_r,
                                       const float* __restrict__ x_t,
                                       size_t xrb, size_t xtb, int l) {
#pragma unroll
    for (int u = 0; u < 4; ++u) {
        int v = l + 16 * u;
        dst[u] = (v < 47) ? x_r[xrb + v] : ((v < 49) ? x_t[xtb + (v - 47)] : 0.0f);
    }
}

__device__ __forceinline__ void unpack12(f2 (&in)[24], const float4* __restrict__ r4) {
#pragma unroll
    for (int u = 0; u < 12; ++u) {
        float4 v = r4[u];
        in[2 * u]     = f2{v.x, v.y};
        in[2 * u + 1] = f2{v.z, v.w};
    }
}

__device__ __forceinline__ void dot4(float (&pre)[4], const f2 (&in)[24],
                                     const f2 (&w)[4][24], float4 init) {
    f2 a0 = f2{init.x, 0.f}, a1 = f2{init.y, 0.f}, a2 = f2{init.z, 0.f}, a3 = f2{init.w, 0.f};
#pragma unroll
    for (int u = 0; u < 24; ++u) {
        a0 = __builtin_elementwise_fma(w[0][u], in[u], a0);
        a1 = __builtin_elementwise_fma(w[1][u], in[u], a1);
        a2 = __builtin_elementwise_fma(w[2][u], in[u], a2);
        a3 = __builtin_elementwise_fma(w[3][u], in[u], a3);
    }
    pre[0] = a0.x + a0.y; pre[1] = a1.x + a1.y;
    pre[2] = a2.x + a2.y; pre[3] = a3.x + a3.y;
}

// amdgpu_waves_per_eu(2,2): target EXACTLY 2 waves/EU -> 256-VGPR budget.
// Default heuristic targeted 4 waves/EU (VGPR_Count=128 in R9/R10 profiles),
// which parked the ~200 loop-invariant weight floats in AGPRs and paid a
// v_accvgpr_read per use in the hot loop (~2x VALU issue inflation).
__global__ __launch_bounds__(320) __attribute__((amdgpu_waves_per_eu(2, 2)))
void adrnn_fused(
    const float* __restrict__ x_r, const float* __restrict__ x_t,
    const float* __restrict__ rWih0, const float* __restrict__ rWhh0,
    const float* __restrict__ rbih0, const float* __restrict__ rbhh0,
    const float* __restrict__ rWih1, const float* __restrict__ rWhh1,
    const float* __restrict__ rbih1, const float* __restrict__ rbhh1,
    const float* __restrict__ tWih0, const float* __restrict__ tWhh0,
    const float* __restrict__ tbih0, const float* __restrict__ tbhh0,
    const float* __restrict__ tWih1, const float* __restrict__ tWhh1,
    const float* __restrict__ tbih1, const float* __restrict__ tbhh1,
    float* __restrict__ r_out, float* __restrict__ t_out)
{
    // Rings. All cross-wave reads touch data written in a PREVIOUS 8-step group
    // (made visible by the group barrier); same-wave RAW ordered by lgkmcnt.
    __shared__ __align__(16) float tring[64][112]; // [x 0..48 | pad | h1 64..110 | pad 111]
    __shared__ __align__(16) float h0ring[16][48]; // h0(s) in slot s&15, [47]=0 pad
    __shared__ __align__(16) float pAring[16][188];// Wih0*x(s)+b0, float4 per unit
    __shared__ __align__(16) float pBring[16][188];// Wih1*h0(s)+b1

    const int tid = threadIdx.x;
    const int wid = tid >> 6;
    const int l   = tid & 63;
    const int j   = l;                    // unit index for waves 0-3
    const int b = blockIdx.x;
    const size_t xr_base = (size_t)b * T_STEPS * 47;
    const size_t xt_base = (size_t)b * T_STEPS * 2;

    // zero-init (waves 0-3) — h1 region + pads of tring, all of h0ring.
    if (tid < 256) {
        for (int k = tid; k < 64 * 48; k += 256) tring[k / 48][64 + (k % 48)] = 0.0f;
        for (int k = tid; k < 16 * 48; k += 256) h0ring[k / 48][k % 48] = 0.0f;
    }

    if (wid == 0) {
        // ===== XA: pA(i) = Wih0 * x(i) + b0  (lag 0, non-recurrent) =====
        f2 w[4][24]; float w48[4]; float4 bias = {0, 0, 0, 0};
#pragma unroll
        for (int g = 0; g < 4; ++g) { w48[g] = 0.f;
#pragma unroll
            for (int u = 0; u < 24; ++u) w[g][u] = f2{0.f, 0.f}; }
        if (j < 47) {
            float bb[4];
#pragma unroll
            for (int g = 0; g < 4; ++g) {
                const int row = g * 47 + j;
#pragma unroll
                for (int u = 0; u < 24; ++u)
                    w[g][u] = f2{rWih0[row * 49 + 2 * u], rWih0[row * 49 + 2 * u + 1]};
                w48[g] = rWih0[row * 49 + 48];
                bb[g] = rbih0[row] + rbhh0[row];
            }
            bias = {bb[0], bb[1], bb[2], bb[3]};
        }
        __syncthreads();
        for (int i = 0; i < TOTAL; ++i) {
            if (i < T_STEPS && j < 47) {
                f2 in[24];
                unpack12(in, (const float4*)&tring[i & 63][0]);
                float x48 = tring[i & 63][48];
                float pre[4];
                dot4(pre, in, w, bias);
                float4 out;
                out.x = fmaf(w48[0], x48, pre[0]);
                out.y = fmaf(w48[1], x48, pre[1]);
                out.z = fmaf(w48[2], x48, pre[2]);
                out.w = fmaf(w48[3], x48, pre[3]);
                *(float4*)&pAring[i & 15][j * 4] = out;
            }
            if ((i & 7) == 7) LDS_BARRIER();
        }
    } else if (wid == 1) {
        // ===== HA: h0(s) = cell(pA(s) + Whh0*h0(s-1))  (lag 8, recurrent) =====
        f2 w[4][24];
#pragma unroll
        for (int g = 0; g < 4; ++g)
#pragma unroll
            for (int u = 0; u < 24; ++u) w[g][u] = f2{0.f, 0.f};
        if (j < 47) {
#pragma unroll
            for (int g = 0; g < 4; ++g) {
                const int row = g * 47 + j;
#pragma unroll
                for (int u = 0; u < 23; ++u)
                    w[g][u] = f2{rWhh0[row * 47 + 2 * u], rWhh0[row * 47 + 2 * u + 1]};
                w[g][23] = f2{rWhh0[row * 47 + 46], 0.f};
            }
        }
        float c0 = 0.f;
        __syncthreads();
        for (int i = 0; i < TOTAL; ++i) {
            const int s = i - 8;
            if (s >= 0 && s < T_STEPS && j < 47) {
                float4 pa = *(const float4*)&pAring[s & 15][j * 4];
                f2 in[24];
                unpack12(in, (const float4*)&h0ring[(s - 1) & 15][0]);
                float pre[4];
                dot4(pre, in, w, pa);
                float iv = sig_f(pre[0]), fv = sig_f(pre[1]);
                float gv = tanh_f(pre[2]), ov = sig_f(pre[3]);
                c0 = fmaf(fv, c0, iv * gv);
                float h = ov * tanh_f(c0);
                h0ring[s & 15][j] = h;
            }
            if ((i & 7) == 7) LDS_BARRIER();
        }
    } else if (wid == 2) {
        // ===== XB: pB(s) = Wih1 * h0(s) + b1  (lag 16, non-recurrent) =====
        f2 w[4][24]; float4 bias = {0, 0, 0, 0};
#pragma unroll
        for (int g = 0; g < 4; ++g)
#pragma unroll
            for (int u = 0; u < 24; ++u) w[g][u] = f2{0.f, 0.f};
        if (j < 47) {
            float bb[4];
#pragma unroll
            for (int g = 0; g < 4; ++g) {
                const int row = g * 47 + j;
#pragma unroll
                for (int u = 0; u < 23; ++u)
                    w[g][u] = f2{rWih1[row * 47 + 2 * u], rWih1[row * 47 + 2 * u + 1]};
                w[g][23] = f2{rWih1[row * 47 + 46], 0.f};
                bb[g] = rbih1[row] + rbhh1[row];
            }
            bias = {bb[0], bb[1], bb[2], bb[3]};
        }
        __syncthreads();
        for (int i = 0; i < TOTAL; ++i) {
            const int s = i - 16;
            if (s >= 0 && s < T_STEPS && j < 47) {
                f2 in[24];
                unpack12(in, (const float4*)&h0ring[s & 15][0]);
                float pre[4];
                dot4(pre, in, w, bias);
                *(float4*)&pBring[s & 15][j * 4] = float4{pre[0], pre[1], pre[2], pre[3]};
            }
            if ((i & 7) == 7) LDS_BARRIER();
        }
    } else if (wid == 3) {
        // ===== HB: h1(s) = cell(pB(s) + Whh1*h1(s-1))  (lag 24, recurrent) =====
        f2 w[4][24];
#pragma unroll
        for (int g = 0; g < 4; ++g)
#pragma unroll
            for (int u = 0; u < 24; ++u) w[g][u] = f2{0.f, 0.f};
        if (j < 47) {
#pragma unroll
            for (int g = 0; g < 4; ++g) {
                const int row = g * 47 + j;
#pragma unroll
                for (int u = 0; u < 23; ++u)
                    w[g][u] = f2{rWhh1[row * 47 + 2 * u], rWhh1[row * 47 + 2 * u + 1]};
                w[g][23] = f2{rWhh1[row * 47 + 46], 0.f};
            }
        }
        float c1 = 0.f;
        __syncthreads();
        for (int i = 0; i < TOTAL; ++i) {
            const int s = i - 24;
            if (s >= 0 && s < T_STEPS && j < 47) {
                float4 pb = *(const float4*)&pBring[s & 15][j * 4];
                f2 in[24];
                unpack12(in, (const float4*)&tring[(s - 1) & 63][64]); // h1(s-1), [111]=0
                float pre[4];
                dot4(pre, in, w, pb);
                float iv = sig_f(pre[0]), fv = sig_f(pre[1]);
                float gv = tanh_f(pre[2]), ov = sig_f(pre[3]);
                c1 = fmaf(fv, c1, iv * gv);
                float h = ov * tanh_f(c1);
                tring[s & 63][64 + j] = h;
                r_out[((size_t)b * T_STEPS + s) * 47 + j] = h;
            }
            if ((i & 7) == 7) LDS_BARRIER();
        }
    } else {
        // ===== TT: t-RNN (lag 32) + x staging (8 ahead) =====
        const int u  = (l >> 2) & 1;
        const int g  = l & 3;
        const int hf = (l >> 3) & 1;
        const int R0 = g * 2 + u;
        // hf=0: input cols 0..47 (x); hf=1: col 48 (x48, scalar) + cols 49..95 (h1, padded)
        f2 wt[24]; float wx48;
        if (hf == 0) {
            wx48 = 0.f;
#pragma unroll
            for (int k = 0; k < 24; ++k)
                wt[k] = f2{tWih0[R0 * 96 + 2 * k], tWih0[R0 * 96 + 2 * k + 1]};
        } else {
            wx48 = tWih0[R0 * 96 + 48];
#pragma unroll
            for (int k = 0; k < 23; ++k)
                wt[k] = f2{tWih0[R0 * 96 + 49 + 2 * k], tWih0[R0 * 96 + 49 + 2 * k + 1]};
            wt[23] = f2{tWih0[R0 * 96 + 95], 0.f};
        }
        const float bT0 = tbih0[R0] + tbhh0[R0];
        const float wh00 = tWhh0[R0 * 2 + 0], wh01 = tWhh0[R0 * 2 + 1];
        const float wi10 = tWih1[R0 * 2 + 0], wi11 = tWih1[R0 * 2 + 1];
        const float wh10 = tWhh1[R0 * 2 + 0], wh11 = tWhh1[R0 * 2 + 1];
        const float bT1 = tbih1[R0] + tbhh1[R0];
        const bool isg = (g == 2);
        const float zm = isg ? 2.f : 1.f, sm = isg ? 2.f : 1.f, sa = isg ? -1.f : 0.f;
        float ht00 = 0.f, ht01 = 0.f, ct0u = 0.f;
        float ht10 = 0.f, ht11 = 0.f, ct1u = 0.f;

        // prologue: stage x(0..7); prefetch regs xa=x(8), xb=x(9), xc=x(10)
        float xa[4] = {0,0,0,0}, xb[4] = {0,0,0,0}, xc[4] = {0,0,0,0};
        if (l < 16) {
            for (int t = 0; t < 8; ++t) {
                float xv[4];
                loadx4(xv, x_r, x_t, xr_base + (size_t)t * 47, xt_base + (size_t)t * 2, l);
#pragma unroll
                for (int uu = 0; uu < 4; ++uu) {
                    int v = l + 16 * uu;
                    if (v < 49) tring[t][v] = xv[uu];
                }
            }
            loadx4(xa, x_r, x_t, xr_base + (size_t)8 * 47,  xt_base + (size_t)8 * 2,  l);
            loadx4(xb, x_r, x_t, xr_base + (size_t)9 * 47,  xt_base + (size_t)9 * 2,  l);
            loadx4(xc, x_r, x_t, xr_base + (size_t)10 * 47, xt_base + (size_t)10 * 2, l);
        }
        __syncthreads();

        for (int i = 0; i < TOTAL; ++i) {
            // staging first: x(i+8) -> tring (consumed by XA next group)
            if (l < 16) {
                const int tw = i + 8;
                if (tw < T_STEPS) {
#pragma unroll
                    for (int uu = 0; uu < 4; ++uu) {
                        int v = l + 16 * uu;
                        if (v < 49) tring[tw & 63][v] = xa[uu];
                    }
                }
#pragma unroll
                for (int uu = 0; uu < 4; ++uu) { xa[uu] = xb[uu]; xb[uu] = xc[uu]; }
                int tl = i + 11;
                if (tl > T_STEPS - 1) tl = T_STEPS - 1;
                loadx4(xc, x_r, x_t, xr_base + (size_t)tl * 47, xt_base + (size_t)tl * 2, l);
            }
            const int s = i - 32;
            if (s >= 0 && s < T_STEPS) {
                f2 in[24];
                unpack12(in, (const float4*)&tring[s & 63][hf ? 64 : 0]);
                float x48 = tring[s & 63][48];
                f2 av = {0, 0}, bv = {0, 0};
#pragma unroll
                for (int k = 0; k < 12; ++k) {
                    av = __builtin_elementwise_fma(wt[2 * k],     in[2 * k],     av);
                    bv = __builtin_elementwise_fma(wt[2 * k + 1], in[2 * k + 1], bv);
                }
                f2 sv = av + bv;
                float part = fmaf(wx48, x48, sv.x + sv.y);
                float pre0 = part + dppf<DPP_ROR8>(part);
                pre0 += bT0 + wh00 * ht00 + wh01 * ht01;
                float a0 = gate_act(pre0, zm, sm, sa);
                float i0 = dppf<DPP_BCAST0>(a0);
                float f0 = dppf<DPP_BCAST1>(a0);
                float g0 = dppf<DPP_BCAST2>(a0);
                float o0 = dppf<DPP_BCAST3>(a0);
                ct0u = fmaf(f0, ct0u, i0 * g0);
                float htu = o0 * tanh_f(ct0u);
                float hto = dppf<DPP_ROR4>(htu);
                ht00 = (u == 0) ? htu : hto;
                ht01 = (u == 0) ? hto : htu;
                float pre1 = bT1 + wi10 * ht00 + wi11 * ht01 + wh10 * ht10 + wh11 * ht11;
                float a1 = gate_act(pre1, zm, sm, sa);
                float ji = dppf<DPP_BCAST0>(a1);
                float jf = dppf<DPP_BCAST1>(a1);
                float jg = dppf<DPP_BCAST2>(a1);
                float jo = dppf<DPP_BCAST3>(a1);
                ct1u = fmaf(jf, ct1u, ji * jg);
                float h1u = jo * tanh_f(ct1u);
                float h1o = dppf<DPP_ROR4>(h1u);
                ht10 = (u == 0) ? h1u : h1o;
                ht11 = (u == 0) ? h1o : h1u;
                if (l == 0) {
                    float2 tv = {ht10, ht11};
                    *reinterpret_cast<float2*>(&t_out[((size_t)b * T_STEPS + s) * 2]) = tv;
                }
            }
            if ((i & 7) == 7) LDS_BARRIER();
        }
    }
}

extern "C" void kernel_launch(void* const* d_in, const int* in_sizes, int n_in,
                              void* d_out, int out_size, void* d_ws, size_t ws_size,
                              hipStream_t stream) {
    const float* x_r   = (const float*)d_in[0];
    const float* x_t   = (const float*)d_in[1];
    const float* rWih0 = (const float*)d_in[2];
    const float* rWhh0 = (const float*)d_in[3];
    const float* rbih0 = (const float*)d_in[4];
    const float* rbhh0 = (const float*)d_in[5];
    const float* rWih1 = (const float*)d_in[6];
    const float* rWhh1 = (const float*)d_in[7];
    const float* rbih1 = (const float*)d_in[8];
    const float* rbhh1 = (const float*)d_in[9];
    const float* tWih0 = (const float*)d_in[10];
    const float* tWhh0 = (const float*)d_in[11];
    const float* tbih0 = (const float*)d_in[12];
    const float* tbhh0 = (const float*)d_in[13];
    const float* tWih1 = (const float*)d_in[14];
    const float* tWhh1 = (const float*)d_in[15];
    const float* tbih1 = (const float*)d_in[16];
    const float* tbhh1 = (const float*)d_in[17];

    float* r_out = (float*)d_out;
    float* t_out = r_out + (size_t)256 * T_STEPS * 47;

    hipLaunchKernelGGL(adrnn_fused, dim3(256), dim3(320), 0, stream,
                       x_r, x_t, rWih0, rWhh0, rbih0, rbhh0, rWih1, rWhh1, rbih1, rbhh1,
                       tWih0, tWhh0, tbih0, tbhh0, tWih1, tWhh1, tbih1, tbhh1,
                       r_out, t_out);
}